// Round 3
// baseline (421.081 us; speedup 1.0000x reference)
//
#include <hip/hip_runtime.h>

// ---------------------------------------------------------------------------
// StandardGCN: 3-layer GCN, N=50000 nodes, E=800000 edges, D=H=128, OUT=2.
// Strategy:
//   - Build CSR (by dst) on device each call: histogram -> scan -> fill.
//   - deg[v] = indeg[v] + 1 (self loop), dis = rsqrt(deg), norm = dis[s]*dis[d].
//   - Layer 1/2: h = A @ W (f32, LDS-staged GEMM), then pull-aggregation:
//       one wave per node, lane owns 2 cols (float2), gathers 512B rows
//       (L3-resident) -> + bias -> relu. No atomics in hot path.
//   - Layer 3: transform first (128->2), then 2-wide aggregation into d_out.
// All f32 (reference tolerance is bf16-level; f32 gives ~1e-6 error).
// ---------------------------------------------------------------------------

__global__ void k_zero_i32(int* __restrict__ p, int n) {
    int i = blockIdx.x * blockDim.x + threadIdx.x;
    if (i < n) p[i] = 0;
}

__global__ void k_hist(const int* __restrict__ dst, int E, int* __restrict__ cnt) {
    int e = blockIdx.x * blockDim.x + threadIdx.x;
    if (e < E) atomicAdd(&cnt[dst[e]], 1);
}

// Block-level exclusive scan (256 elems/block) + block sums.
__global__ void k_scanA(const int* __restrict__ cnt, int n,
                        int* __restrict__ rowptr, int* __restrict__ bsum) {
    __shared__ int s[256];
    int t = threadIdx.x;
    int i = blockIdx.x * 256 + t;
    int v = (i < n) ? cnt[i] : 0;
    s[t] = v;
    __syncthreads();
    for (int off = 1; off < 256; off <<= 1) {
        int u = (t >= off) ? s[t - off] : 0;
        __syncthreads();
        s[t] += u;
        __syncthreads();
    }
    if (i < n) rowptr[i] = s[t] - v;  // exclusive
    if (t == 255) bsum[blockIdx.x] = s[255];
}

// Single-block exclusive scan of block sums (nb <= 256).
__global__ void k_scanB(int* __restrict__ bsum, int nb) {
    __shared__ int s[256];
    int t = threadIdx.x;
    int v = (t < nb) ? bsum[t] : 0;
    s[t] = v;
    __syncthreads();
    for (int off = 1; off < 256; off <<= 1) {
        int u = (t >= off) ? s[t - off] : 0;
        __syncthreads();
        s[t] += u;
        __syncthreads();
    }
    if (t < nb) bsum[t] = s[t] - v;
}

__global__ void k_scanC(int* __restrict__ rowptr, const int* __restrict__ bsum,
                        int n, int E) {
    int i = blockIdx.x * 256 + threadIdx.x;
    if (i < n) rowptr[i] += bsum[blockIdx.x];
    if (i == 0) rowptr[n] = E;
}

__global__ void k_dis_cursor(const int* __restrict__ cnt, const int* __restrict__ rowptr,
                             float* __restrict__ dis, int* __restrict__ cursor, int n) {
    int i = blockIdx.x * blockDim.x + threadIdx.x;
    if (i < n) {
        dis[i] = rsqrtf((float)(cnt[i] + 1));  // +1 for self loop
        cursor[i] = rowptr[i];
    }
}

__global__ void k_fill(const int* __restrict__ src, const int* __restrict__ dst, int E,
                       const float* __restrict__ dis, int* __restrict__ cursor,
                       int* __restrict__ csr_src, float* __restrict__ csr_w) {
    int e = blockIdx.x * blockDim.x + threadIdx.x;
    if (e < E) {
        int s = src[e], d = dst[e];
        int pos = atomicAdd(&cursor[d], 1);
        csr_src[pos] = s;
        csr_w[pos] = dis[s] * dis[d];
    }
}

// C[n x 128] = A[n x 128] @ W[128 x 128], f32. 64 rows/block, 256 threads.
// Each thread computes 8 rows x 4 cols. W (64KB) + A-tile (32KB) in LDS.
__global__ __launch_bounds__(256) void k_gemm128(const float* __restrict__ A,
                                                 const float* __restrict__ W,
                                                 float* __restrict__ C, int n) {
    __shared__ float Ws[128 * 128];
    __shared__ float As[64 * 128];
    int t = threadIdx.x;
    int r0 = blockIdx.x * 64;

    // stage W: 4096 float4, 16 per thread
    for (int i = t; i < 128 * 128 / 4; i += 256) {
        ((float4*)Ws)[i] = ((const float4*)W)[i];
    }
    // stage A rows r0..r0+63: 2048 float4, 8 per thread
    for (int i = t; i < 64 * 128 / 4; i += 256) {
        int gr = r0 + (i >> 5);
        float4 val = (gr < n) ? ((const float4*)A)[(size_t)gr * 32 + (i & 31)]
                              : make_float4(0.f, 0.f, 0.f, 0.f);
        ((float4*)As)[i] = val;
    }
    __syncthreads();

    int c4 = (t & 31) * 4;       // 4 consecutive cols
    int r8 = (t >> 5) * 8;       // 8 consecutive rows
    float acc[8][4] = {};
#pragma unroll 4
    for (int k = 0; k < 128; k++) {
        float4 w4 = *(const float4*)&Ws[k * 128 + c4];
#pragma unroll
        for (int i = 0; i < 8; i++) {
            float a = As[(r8 + i) * 128 + k];
            acc[i][0] += a * w4.x;
            acc[i][1] += a * w4.y;
            acc[i][2] += a * w4.z;
            acc[i][3] += a * w4.w;
        }
    }
#pragma unroll
    for (int i = 0; i < 8; i++) {
        int r = r0 + r8 + i;
        if (r < n) {
            *(float4*)&C[(size_t)r * 128 + c4] =
                make_float4(acc[i][0], acc[i][1], acc[i][2], acc[i][3]);
        }
    }
}

// Pull aggregation, dim=128. One wave per node; lane owns 2 cols (float2).
__global__ __launch_bounds__(256) void k_agg128(const float* __restrict__ H,
                                                const int* __restrict__ rowptr,
                                                const int* __restrict__ csr_src,
                                                const float* __restrict__ csr_w,
                                                const float* __restrict__ dis,
                                                const float* __restrict__ bias,
                                                float* __restrict__ O, int n, int do_relu) {
    int wid = threadIdx.x >> 6;
    int lane = threadIdx.x & 63;
    int v = blockIdx.x * 4 + wid;
    if (v >= n) return;

    float dv = dis[v];
    float sw = dv * dv;  // self-loop norm
    float2 h2 = ((const float2*)(H + (size_t)v * 128))[lane];
    float ax = h2.x * sw, ay = h2.y * sw;

    int e = rowptr[v], end = rowptr[v + 1];
    for (; e + 4 <= end; e += 4) {
        int s0 = csr_src[e], s1 = csr_src[e + 1], s2 = csr_src[e + 2], s3 = csr_src[e + 3];
        float w0 = csr_w[e], w1 = csr_w[e + 1], w2 = csr_w[e + 2], w3 = csr_w[e + 3];
        float2 a0 = ((const float2*)(H + (size_t)s0 * 128))[lane];
        float2 a1 = ((const float2*)(H + (size_t)s1 * 128))[lane];
        float2 a2 = ((const float2*)(H + (size_t)s2 * 128))[lane];
        float2 a3 = ((const float2*)(H + (size_t)s3 * 128))[lane];
        ax += a0.x * w0 + a1.x * w1 + a2.x * w2 + a3.x * w3;
        ay += a0.y * w0 + a1.y * w1 + a2.y * w2 + a3.y * w3;
    }
    for (; e < end; e++) {
        int s = csr_src[e];
        float w = csr_w[e];
        float2 a = ((const float2*)(H + (size_t)s * 128))[lane];
        ax += a.x * w;
        ay += a.y * w;
    }

    float2 b2 = ((const float2*)bias)[lane];
    ax += b2.x;
    ay += b2.y;
    if (do_relu) {
        ax = fmaxf(ax, 0.f);
        ay = fmaxf(ay, 0.f);
    }
    ((float2*)(O + (size_t)v * 128))[lane] = make_float2(ax, ay);
}

// T[n x 2] = A[n x 128] @ W3[128 x 2]. One thread per node.
__global__ __launch_bounds__(256) void k_gemm_out(const float* __restrict__ A,
                                                  const float* __restrict__ W,
                                                  float* __restrict__ T, int n) {
    __shared__ float Wls[256];
    if (threadIdx.x < 256) Wls[threadIdx.x] = W[threadIdx.x];
    __syncthreads();
    int v = blockIdx.x * blockDim.x + threadIdx.x;
    if (v >= n) return;
    const float4* Av = (const float4*)(A + (size_t)v * 128);
    float acc0 = 0.f, acc1 = 0.f;
#pragma unroll
    for (int i = 0; i < 32; i++) {
        float4 a = Av[i];
        int k = i * 4;
        acc0 += a.x * Wls[(k + 0) * 2] + a.y * Wls[(k + 1) * 2] +
                a.z * Wls[(k + 2) * 2] + a.w * Wls[(k + 3) * 2];
        acc1 += a.x * Wls[(k + 0) * 2 + 1] + a.y * Wls[(k + 1) * 2 + 1] +
                a.z * Wls[(k + 2) * 2 + 1] + a.w * Wls[(k + 3) * 2 + 1];
    }
    ((float2*)T)[v] = make_float2(acc0, acc1);
}

// Final aggregation, dim=2, one thread per node, writes d_out.
__global__ __launch_bounds__(256) void k_agg2(const float* __restrict__ T,
                                              const int* __restrict__ rowptr,
                                              const int* __restrict__ csr_src,
                                              const float* __restrict__ csr_w,
                                              const float* __restrict__ dis,
                                              const float* __restrict__ b3,
                                              float* __restrict__ out, int n) {
    int v = blockIdx.x * blockDim.x + threadIdx.x;
    if (v >= n) return;
    float dv = dis[v];
    float sw = dv * dv;
    float2 tv = ((const float2*)T)[v];
    float a0 = tv.x * sw, a1 = tv.y * sw;
    int end = rowptr[v + 1];
    for (int e = rowptr[v]; e < end; e++) {
        int s = csr_src[e];
        float w = csr_w[e];
        float2 hs = ((const float2*)T)[s];
        a0 += hs.x * w;
        a1 += hs.y * w;
    }
    ((float2*)out)[v] = make_float2(a0 + b3[0], a1 + b3[1]);
}

extern "C" void kernel_launch(void* const* d_in, const int* in_sizes, int n_in,
                              void* d_out, int out_size, void* d_ws, size_t ws_size,
                              hipStream_t stream) {
    const float* x  = (const float*)d_in[0];
    const int* edge = (const int*)d_in[1];
    const float* W1 = (const float*)d_in[2];
    const float* b1 = (const float*)d_in[3];
    const float* W2 = (const float*)d_in[4];
    const float* b2 = (const float*)d_in[5];
    const float* W3 = (const float*)d_in[6];
    const float* b3 = (const float*)d_in[7];

    const int n = in_sizes[0] / 128;   // 50000
    const int E = in_sizes[1] / 2;     // 800000
    const int* src = edge;
    const int* dst = edge + E;

    // Workspace carve (aligned 256B). Total ~58.5 MB.
    char* p = (char*)d_ws;
    auto alloc = [&](size_t bytes) -> void* {
        void* r = (void*)p;
        p += ((bytes + 255) / 256) * 256;
        return r;
    };
    int*   cnt     = (int*)alloc((size_t)n * 4);
    int*   rowptr  = (int*)alloc((size_t)(n + 1) * 4);
    int*   cursor  = (int*)alloc((size_t)n * 4);
    float* dis     = (float*)alloc((size_t)n * 4);
    int*   bsum    = (int*)alloc(256 * 4);
    int*   csr_src = (int*)alloc((size_t)E * 4);
    float* csr_w   = (float*)alloc((size_t)E * 4);
    float* t3      = (float*)alloc((size_t)n * 2 * 4);
    float* bufA    = (float*)alloc((size_t)n * 128 * 4);
    float* bufB    = (float*)alloc((size_t)n * 128 * 4);
    (void)ws_size;

    const int nscan = (n + 255) / 256;          // 196 blocks (<=256 required)
    const int eblk  = (E + 255) / 256;
    const int nblk  = (n + 255) / 256;

    // --- CSR build ---
    k_zero_i32<<<nblk, 256, 0, stream>>>(cnt, n);
    k_hist<<<eblk, 256, 0, stream>>>(dst, E, cnt);
    k_scanA<<<nscan, 256, 0, stream>>>(cnt, n, rowptr, bsum);
    k_scanB<<<1, 256, 0, stream>>>(bsum, nscan);
    k_scanC<<<nscan, 256, 0, stream>>>(rowptr, bsum, n, E);
    k_dis_cursor<<<nblk, 256, 0, stream>>>(cnt, rowptr, dis, cursor, n);
    k_fill<<<eblk, 256, 0, stream>>>(src, dst, E, dis, cursor, csr_src, csr_w);

    const int gblk = (n + 63) / 64;   // gemm128 blocks
    const int ablk = (n + 3) / 4;     // agg128 blocks (4 waves/block)

    // --- Layer 1 ---
    k_gemm128<<<gblk, 256, 0, stream>>>(x, W1, bufA, n);
    k_agg128<<<ablk, 256, 0, stream>>>(bufA, rowptr, csr_src, csr_w, dis, b1, bufB, n, 1);
    // --- Layer 2 ---
    k_gemm128<<<gblk, 256, 0, stream>>>(bufB, W2, bufA, n);
    k_agg128<<<ablk, 256, 0, stream>>>(bufA, rowptr, csr_src, csr_w, dis, b2, bufB, n, 1);
    // --- Layer 3 (transform first: aggregation is linear) ---
    k_gemm_out<<<nblk, 256, 0, stream>>>(bufB, W3, t3, n);
    k_agg2<<<nblk, 256, 0, stream>>>(t3, rowptr, csr_src, csr_w, dis, b3, (float*)d_out, n);
}

// Round 4
// 391.758 us; speedup vs baseline: 1.0748x; 1.0748x over previous
//
#include <hip/hip_runtime.h>

// ---------------------------------------------------------------------------
// StandardGCN: 3-layer GCN, N=50000 nodes, E=800000 edges, D=H=128, OUT=2.
//   - CSR build (by dst) on device: histogram -> scan -> fill (src only;
//     norm weights recomputed in agg from dis[] to halve scatter traffic).
//   - Layer 1/2: h = A @ W (f32, 48KB-LDS GEMM: A-tile 32KB + W chunk 16KB
//     -> 3 blocks/CU vs 1 before), then pull-aggregation (wave/node).
//   - Layer 3: transform first (128->2), then 2-wide aggregation.
// All f32 (threshold is bf16-level; f32 gives ~2e-4 absmax, 13x margin).
// ---------------------------------------------------------------------------

__global__ void k_zero_i32(int* __restrict__ p, int n) {
    int i = blockIdx.x * blockDim.x + threadIdx.x;
    if (i < n) p[i] = 0;
}

__global__ void k_hist(const int* __restrict__ dst, int E, int* __restrict__ cnt) {
    int e = blockIdx.x * blockDim.x + threadIdx.x;
    if (e < E) atomicAdd(&cnt[dst[e]], 1);
}

// Block-level exclusive scan (256 elems/block) + block sums.
__global__ void k_scanA(const int* __restrict__ cnt, int n,
                        int* __restrict__ rowptr, int* __restrict__ bsum) {
    __shared__ int s[256];
    int t = threadIdx.x;
    int i = blockIdx.x * 256 + t;
    int v = (i < n) ? cnt[i] : 0;
    s[t] = v;
    __syncthreads();
    for (int off = 1; off < 256; off <<= 1) {
        int u = (t >= off) ? s[t - off] : 0;
        __syncthreads();
        s[t] += u;
        __syncthreads();
    }
    if (i < n) rowptr[i] = s[t] - v;  // exclusive
    if (t == 255) bsum[blockIdx.x] = s[255];
}

// Single-block exclusive scan of block sums (nb <= 256).
__global__ void k_scanB(int* __restrict__ bsum, int nb) {
    __shared__ int s[256];
    int t = threadIdx.x;
    int v = (t < nb) ? bsum[t] : 0;
    s[t] = v;
    __syncthreads();
    for (int off = 1; off < 256; off <<= 1) {
        int u = (t >= off) ? s[t - off] : 0;
        __syncthreads();
        s[t] += u;
        __syncthreads();
    }
    if (t < nb) bsum[t] = s[t] - v;
}

__global__ void k_scanC(int* __restrict__ rowptr, const int* __restrict__ bsum,
                        int n, int E) {
    int i = blockIdx.x * 256 + threadIdx.x;
    if (i < n) rowptr[i] += bsum[blockIdx.x];
    if (i == 0) rowptr[n] = E;
}

__global__ void k_dis_cursor(const int* __restrict__ cnt, const int* __restrict__ rowptr,
                             float* __restrict__ dis, int* __restrict__ cursor, int n) {
    int i = blockIdx.x * blockDim.x + threadIdx.x;
    if (i < n) {
        dis[i] = rsqrtf((float)(cnt[i] + 1));  // +1 for self loop
        cursor[i] = rowptr[i];
    }
}

// Counting-sort fill: only src index (4B/edge scatter; weights recomputed later).
__global__ void k_fill(const int* __restrict__ src, const int* __restrict__ dst, int E,
                       int* __restrict__ cursor, int* __restrict__ csr_src) {
    int e = blockIdx.x * blockDim.x + threadIdx.x;
    if (e < E) {
        int d = dst[e];
        int pos = atomicAdd(&cursor[d], 1);
        csr_src[pos] = src[e];
    }
}

// C[n x 128] = A[n x 128] @ W[128 x 128], f32. 64 rows/block, 256 threads.
// LDS: A-tile 32KB + 16KB W-chunk (32 k's, reused 4x) = 48KB -> 3 blocks/CU.
__global__ __launch_bounds__(256) void k_gemm128(const float* __restrict__ A,
                                                 const float* __restrict__ W,
                                                 float* __restrict__ C, int n) {
    __shared__ float As[64 * 128];
    __shared__ float Wc[32 * 128];
    int t = threadIdx.x;
    int r0 = blockIdx.x * 64;

    // stage A rows r0..r0+63: 2048 float4, 8 per thread
    for (int i = t; i < 64 * 128 / 4; i += 256) {
        int gr = r0 + (i >> 5);
        float4 val = (gr < n) ? ((const float4*)A)[(size_t)gr * 32 + (i & 31)]
                              : make_float4(0.f, 0.f, 0.f, 0.f);
        ((float4*)As)[i] = val;
    }

    int c4 = (t & 31) * 4;       // 4 consecutive cols
    int r8 = (t >> 5) * 8;       // 8 consecutive rows
    float acc[8][4] = {};

    for (int kc = 0; kc < 4; kc++) {
        __syncthreads();
        // stage W rows kc*32..kc*32+31: 1024 float4, 4 per thread
        for (int i = t; i < 32 * 128 / 4; i += 256) {
            ((float4*)Wc)[i] = ((const float4*)W)[kc * 1024 + i];
        }
        __syncthreads();
#pragma unroll
        for (int kk = 0; kk < 32; kk++) {
            float4 w4 = *(const float4*)&Wc[kk * 128 + c4];
            int k = kc * 32 + kk;
#pragma unroll
            for (int i = 0; i < 8; i++) {
                float a = As[(r8 + i) * 128 + k];
                acc[i][0] += a * w4.x;
                acc[i][1] += a * w4.y;
                acc[i][2] += a * w4.z;
                acc[i][3] += a * w4.w;
            }
        }
    }
#pragma unroll
    for (int i = 0; i < 8; i++) {
        int r = r0 + r8 + i;
        if (r < n) {
            *(float4*)&C[(size_t)r * 128 + c4] =
                make_float4(acc[i][0], acc[i][1], acc[i][2], acc[i][3]);
        }
    }
}

// Pull aggregation, dim=128. One wave per node; lane owns 2 cols (float2).
// Edge weight dis[s]*dis[v] computed on the fly (dis is 200KB, L2-hot).
__global__ __launch_bounds__(256) void k_agg128(const float* __restrict__ H,
                                                const int* __restrict__ rowptr,
                                                const int* __restrict__ csr_src,
                                                const float* __restrict__ dis,
                                                const float* __restrict__ bias,
                                                float* __restrict__ O, int n, int do_relu) {
    int wid = threadIdx.x >> 6;
    int lane = threadIdx.x & 63;
    int v = blockIdx.x * 4 + wid;
    if (v >= n) return;

    float dv = dis[v];
    float sw = dv * dv;  // self-loop norm
    float2 h2 = ((const float2*)(H + (size_t)v * 128))[lane];
    float ax = h2.x * sw, ay = h2.y * sw;

    int e = rowptr[v], end = rowptr[v + 1];
    for (; e + 4 <= end; e += 4) {
        int s0 = csr_src[e], s1 = csr_src[e + 1], s2 = csr_src[e + 2], s3 = csr_src[e + 3];
        float w0 = dis[s0] * dv, w1 = dis[s1] * dv, w2 = dis[s2] * dv, w3 = dis[s3] * dv;
        float2 a0 = ((const float2*)(H + (size_t)s0 * 128))[lane];
        float2 a1 = ((const float2*)(H + (size_t)s1 * 128))[lane];
        float2 a2 = ((const float2*)(H + (size_t)s2 * 128))[lane];
        float2 a3 = ((const float2*)(H + (size_t)s3 * 128))[lane];
        ax += a0.x * w0 + a1.x * w1 + a2.x * w2 + a3.x * w3;
        ay += a0.y * w0 + a1.y * w1 + a2.y * w2 + a3.y * w3;
    }
    for (; e < end; e++) {
        int s = csr_src[e];
        float w = dis[s] * dv;
        float2 a = ((const float2*)(H + (size_t)s * 128))[lane];
        ax += a.x * w;
        ay += a.y * w;
    }

    float2 b2 = ((const float2*)bias)[lane];
    ax += b2.x;
    ay += b2.y;
    if (do_relu) {
        ax = fmaxf(ax, 0.f);
        ay = fmaxf(ay, 0.f);
    }
    ((float2*)(O + (size_t)v * 128))[lane] = make_float2(ax, ay);
}

// T[n x 2] = A[n x 128] @ W3[128 x 2]. One thread per node.
__global__ __launch_bounds__(256) void k_gemm_out(const float* __restrict__ A,
                                                  const float* __restrict__ W,
                                                  float* __restrict__ T, int n) {
    __shared__ float Wls[256];
    if (threadIdx.x < 256) Wls[threadIdx.x] = W[threadIdx.x];
    __syncthreads();
    int v = blockIdx.x * blockDim.x + threadIdx.x;
    if (v >= n) return;
    const float4* Av = (const float4*)(A + (size_t)v * 128);
    float acc0 = 0.f, acc1 = 0.f;
#pragma unroll
    for (int i = 0; i < 32; i++) {
        float4 a = Av[i];
        int k = i * 4;
        acc0 += a.x * Wls[(k + 0) * 2] + a.y * Wls[(k + 1) * 2] +
                a.z * Wls[(k + 2) * 2] + a.w * Wls[(k + 3) * 2];
        acc1 += a.x * Wls[(k + 0) * 2 + 1] + a.y * Wls[(k + 1) * 2 + 1] +
                a.z * Wls[(k + 2) * 2 + 1] + a.w * Wls[(k + 3) * 2 + 1];
    }
    ((float2*)T)[v] = make_float2(acc0, acc1);
}

// Final aggregation, dim=2, one thread per node, writes d_out.
__global__ __launch_bounds__(256) void k_agg2(const float* __restrict__ T,
                                              const int* __restrict__ rowptr,
                                              const int* __restrict__ csr_src,
                                              const float* __restrict__ dis,
                                              const float* __restrict__ b3,
                                              float* __restrict__ out, int n) {
    int v = blockIdx.x * blockDim.x + threadIdx.x;
    if (v >= n) return;
    float dv = dis[v];
    float sw = dv * dv;
    float2 tv = ((const float2*)T)[v];
    float a0 = tv.x * sw, a1 = tv.y * sw;
    int end = rowptr[v + 1];
    for (int e = rowptr[v]; e < end; e++) {
        int s = csr_src[e];
        float w = dis[s] * dv;
        float2 hs = ((const float2*)T)[s];
        a0 += hs.x * w;
        a1 += hs.y * w;
    }
    ((float2*)out)[v] = make_float2(a0 + b3[0], a1 + b3[1]);
}

extern "C" void kernel_launch(void* const* d_in, const int* in_sizes, int n_in,
                              void* d_out, int out_size, void* d_ws, size_t ws_size,
                              hipStream_t stream) {
    const float* x  = (const float*)d_in[0];
    const int* edge = (const int*)d_in[1];
    const float* W1 = (const float*)d_in[2];
    const float* b1 = (const float*)d_in[3];
    const float* W2 = (const float*)d_in[4];
    const float* b2 = (const float*)d_in[5];
    const float* W3 = (const float*)d_in[6];
    const float* b3 = (const float*)d_in[7];

    const int n = in_sizes[0] / 128;   // 50000
    const int E = in_sizes[1] / 2;     // 800000
    const int* src = edge;
    const int* dst = edge + E;

    // Workspace carve (aligned 256B).
    char* p = (char*)d_ws;
    auto alloc = [&](size_t bytes) -> void* {
        void* r = (void*)p;
        p += ((bytes + 255) / 256) * 256;
        return r;
    };
    int*   cnt     = (int*)alloc((size_t)n * 4);
    int*   rowptr  = (int*)alloc((size_t)(n + 1) * 4);
    int*   cursor  = (int*)alloc((size_t)n * 4);
    float* dis     = (float*)alloc((size_t)n * 4);
    int*   bsum    = (int*)alloc(256 * 4);
    int*   csr_src = (int*)alloc((size_t)E * 4);
    float* t3      = (float*)alloc((size_t)n * 2 * 4);
    float* bufA    = (float*)alloc((size_t)n * 128 * 4);
    float* bufB    = (float*)alloc((size_t)n * 128 * 4);
    (void)ws_size;

    const int nscan = (n + 255) / 256;          // 196 blocks (<=256 required)
    const int eblk  = (E + 255) / 256;
    const int nblk  = (n + 255) / 256;

    // --- CSR build ---
    k_zero_i32<<<nblk, 256, 0, stream>>>(cnt, n);
    k_hist<<<eblk, 256, 0, stream>>>(dst, E, cnt);
    k_scanA<<<nscan, 256, 0, stream>>>(cnt, n, rowptr, bsum);
    k_scanB<<<1, 256, 0, stream>>>(bsum, nscan);
    k_scanC<<<nscan, 256, 0, stream>>>(rowptr, bsum, n, E);
    k_dis_cursor<<<nblk, 256, 0, stream>>>(cnt, rowptr, dis, cursor, n);
    k_fill<<<eblk, 256, 0, stream>>>(src, dst, E, cursor, csr_src);

    const int gblk = (n + 63) / 64;   // gemm128 blocks
    const int ablk = (n + 3) / 4;     // agg128 blocks (4 waves/block)

    // --- Layer 1 ---
    k_gemm128<<<gblk, 256, 0, stream>>>(x, W1, bufA, n);
    k_agg128<<<ablk, 256, 0, stream>>>(bufA, rowptr, csr_src, dis, b1, bufB, n, 1);
    // --- Layer 2 ---
    k_gemm128<<<gblk, 256, 0, stream>>>(bufB, W2, bufA, n);
    k_agg128<<<ablk, 256, 0, stream>>>(bufA, rowptr, csr_src, dis, b2, bufB, n, 1);
    // --- Layer 3 (transform first: aggregation is linear) ---
    k_gemm_out<<<nblk, 256, 0, stream>>>(bufB, W3, t3, n);
    k_agg2<<<nblk, 256, 0, stream>>>(t3, rowptr, csr_src, dis, b3, (float*)d_out, n);
}

// Round 9
// 348.762 us; speedup vs baseline: 1.2074x; 1.1233x over previous
//
#include <hip/hip_runtime.h>

// ---------------------------------------------------------------------------
// StandardGCN: 3-layer GCN, N=50000 nodes, E=800000 edges, D=H=128, OUT=2.
//   - CSR build (by dst) on device: memset+histogram -> scan -> fill (src only).
//   - Layer 1/2: h = A @ W (f32 compute, 48KB-LDS GEMM) -> **bf16 H** (halves
//     the 8-XCD L2-miss gather traffic: round-4 profile showed agg fetching
//     188MB/dispatch = 8 XCDs re-streaming the 25.6MB f32 table from L3).
//     Aggregation gathers bf16 rows, accumulates f32, +bias+relu -> f32 out.
//   - Layer 3: transform first (128->2, f32), then 2-wide aggregation.
// ---------------------------------------------------------------------------

typedef unsigned short ushort_t;
typedef unsigned int uint_t;

static __device__ __forceinline__ ushort_t f2bf(float f) {
    uint_t u = __float_as_uint(f);
    u += 0x7FFFu + ((u >> 16) & 1u);   // round-to-nearest-even
    return (ushort_t)(u >> 16);
}
static __device__ __forceinline__ float bf_lo(uint_t u) {  // low 16 bits
    return __uint_as_float(u << 16);
}
static __device__ __forceinline__ float bf_hi(uint_t u) {  // high 16 bits
    return __uint_as_float(u & 0xFFFF0000u);
}

__global__ void k_hist(const int* __restrict__ dst, int E, int* __restrict__ cnt) {
    int e = blockIdx.x * blockDim.x + threadIdx.x;
    if (e < E) atomicAdd(&cnt[dst[e]], 1);
}

// Block-level exclusive scan (256 elems/block) + block sums.
__global__ void k_scanA(const int* __restrict__ cnt, int n,
                        int* __restrict__ rowptr, int* __restrict__ bsum) {
    __shared__ int s[256];
    int t = threadIdx.x;
    int i = blockIdx.x * 256 + t;
    int v = (i < n) ? cnt[i] : 0;
    s[t] = v;
    __syncthreads();
    for (int off = 1; off < 256; off <<= 1) {
        int u = (t >= off) ? s[t - off] : 0;
        __syncthreads();
        s[t] += u;
        __syncthreads();
    }
    if (i < n) rowptr[i] = s[t] - v;  // exclusive
    if (t == 255) bsum[blockIdx.x] = s[255];
}

// Single-block exclusive scan of block sums (nb <= 256).
__global__ void k_scanB(int* __restrict__ bsum, int nb) {
    __shared__ int s[256];
    int t = threadIdx.x;
    int v = (t < nb) ? bsum[t] : 0;
    s[t] = v;
    __syncthreads();
    for (int off = 1; off < 256; off <<= 1) {
        int u = (t >= off) ? s[t - off] : 0;
        __syncthreads();
        s[t] += u;
        __syncthreads();
    }
    if (t < nb) bsum[t] = s[t] - v;
}

// Finalize rowptr, init cursor, compute dis = rsqrt(deg+1). (fused, saves launches)
__global__ void k_scanC(int* __restrict__ rowptr, const int* __restrict__ bsum,
                        const int* __restrict__ cnt, float* __restrict__ dis,
                        int* __restrict__ cursor, int n, int E) {
    int i = blockIdx.x * 256 + threadIdx.x;
    if (i < n) {
        int r = rowptr[i] + bsum[blockIdx.x];
        rowptr[i] = r;
        cursor[i] = r;
        dis[i] = rsqrtf((float)(cnt[i] + 1));
    }
    if (i == 0) rowptr[n] = E;
}

// Counting-sort fill: only src index (4B/edge scatter).
__global__ void k_fill(const int* __restrict__ src, const int* __restrict__ dst, int E,
                       int* __restrict__ cursor, int* __restrict__ csr_src) {
    int e = blockIdx.x * blockDim.x + threadIdx.x;
    if (e < E) {
        int d = dst[e];
        int pos = atomicAdd(&cursor[d], 1);
        csr_src[pos] = src[e];
    }
}

// C[n x 128](bf16) = A[n x 128](f32) @ W[128 x 128](f32). 64 rows/block.
// LDS: A-tile 32KB + W chunk 16KB = 48KB -> 3 blocks/CU.
__global__ __launch_bounds__(256) void k_gemm128(const float* __restrict__ A,
                                                 const float* __restrict__ W,
                                                 ushort_t* __restrict__ C, int n) {
    __shared__ float As[64 * 128];
    __shared__ float Wc[32 * 128];
    int t = threadIdx.x;
    int r0 = blockIdx.x * 64;

    for (int i = t; i < 64 * 128 / 4; i += 256) {
        int gr = r0 + (i >> 5);
        float4 val = (gr < n) ? ((const float4*)A)[(size_t)gr * 32 + (i & 31)]
                              : make_float4(0.f, 0.f, 0.f, 0.f);
        ((float4*)As)[i] = val;
    }

    int c4 = (t & 31) * 4;       // 4 consecutive cols
    int r8 = (t >> 5) * 8;       // 8 consecutive rows
    float acc[8][4] = {};

    for (int kc = 0; kc < 4; kc++) {
        __syncthreads();
        for (int i = t; i < 32 * 128 / 4; i += 256) {
            ((float4*)Wc)[i] = ((const float4*)W)[kc * 1024 + i];
        }
        __syncthreads();
#pragma unroll
        for (int kk = 0; kk < 32; kk++) {
            float4 w4 = *(const float4*)&Wc[kk * 128 + c4];
            int k = kc * 32 + kk;
#pragma unroll
            for (int i = 0; i < 8; i++) {
                float a = As[(r8 + i) * 128 + k];
                acc[i][0] += a * w4.x;
                acc[i][1] += a * w4.y;
                acc[i][2] += a * w4.z;
                acc[i][3] += a * w4.w;
            }
        }
    }
#pragma unroll
    for (int i = 0; i < 8; i++) {
        int r = r0 + r8 + i;
        if (r < n) {
            ushort4 o;
            o.x = f2bf(acc[i][0]);
            o.y = f2bf(acc[i][1]);
            o.z = f2bf(acc[i][2]);
            o.w = f2bf(acc[i][3]);
            *(ushort4*)&C[(size_t)r * 128 + c4] = o;
        }
    }
}

// Pull aggregation, dim=128, H in bf16. One wave/node; lane owns 2 cols (1 uint).
// Edge weight dis[s]*dis[v] computed on the fly. f32 accumulate, f32 output.
__global__ __launch_bounds__(256) void k_agg128(const ushort_t* __restrict__ H,
                                                const int* __restrict__ rowptr,
                                                const int* __restrict__ csr_src,
                                                const float* __restrict__ dis,
                                                const float* __restrict__ bias,
                                                float* __restrict__ O, int n, int do_relu) {
    int wid = threadIdx.x >> 6;
    int lane = threadIdx.x & 63;
    int v = blockIdx.x * 4 + wid;
    if (v >= n) return;

    float dv = dis[v];
    float sw = dv * dv;  // self-loop norm
    uint_t h2 = ((const uint_t*)(H + (size_t)v * 128))[lane];
    float ax = bf_lo(h2) * sw, ay = bf_hi(h2) * sw;

    int e = rowptr[v], end = rowptr[v + 1];
    for (; e + 4 <= end; e += 4) {
        int s0 = csr_src[e], s1 = csr_src[e + 1], s2 = csr_src[e + 2], s3 = csr_src[e + 3];
        float w0 = dis[s0] * dv, w1 = dis[s1] * dv, w2 = dis[s2] * dv, w3 = dis[s3] * dv;
        uint_t a0 = ((const uint_t*)(H + (size_t)s0 * 128))[lane];
        uint_t a1 = ((const uint_t*)(H + (size_t)s1 * 128))[lane];
        uint_t a2 = ((const uint_t*)(H + (size_t)s2 * 128))[lane];
        uint_t a3 = ((const uint_t*)(H + (size_t)s3 * 128))[lane];
        ax += bf_lo(a0) * w0 + bf_lo(a1) * w1 + bf_lo(a2) * w2 + bf_lo(a3) * w3;
        ay += bf_hi(a0) * w0 + bf_hi(a1) * w1 + bf_hi(a2) * w2 + bf_hi(a3) * w3;
    }
    for (; e < end; e++) {
        int s = csr_src[e];
        float w = dis[s] * dv;
        uint_t a = ((const uint_t*)(H + (size_t)s * 128))[lane];
        ax += bf_lo(a) * w;
        ay += bf_hi(a) * w;
    }

    float2 b2 = ((const float2*)bias)[lane];
    ax += b2.x;
    ay += b2.y;
    if (do_relu) {
        ax = fmaxf(ax, 0.f);
        ay = fmaxf(ay, 0.f);
    }
    ((float2*)(O + (size_t)v * 128))[lane] = make_float2(ax, ay);
}

// T[n x 2] = A[n x 128] @ W3[128 x 2]. One thread per node. (f32)
__global__ __launch_bounds__(256) void k_gemm_out(const float* __restrict__ A,
                                                  const float* __restrict__ W,
                                                  float* __restrict__ T, int n) {
    __shared__ float Wls[256];
    if (threadIdx.x < 256) Wls[threadIdx.x] = W[threadIdx.x];
    __syncthreads();
    int v = blockIdx.x * blockDim.x + threadIdx.x;
    if (v >= n) return;
    const float4* Av = (const float4*)(A + (size_t)v * 128);
    float acc0 = 0.f, acc1 = 0.f;
#pragma unroll
    for (int i = 0; i < 32; i++) {
        float4 a = Av[i];
        int k = i * 4;
        acc0 += a.x * Wls[(k + 0) * 2] + a.y * Wls[(k + 1) * 2] +
                a.z * Wls[(k + 2) * 2] + a.w * Wls[(k + 3) * 2];
        acc1 += a.x * Wls[(k + 0) * 2 + 1] + a.y * Wls[(k + 1) * 2 + 1] +
                a.z * Wls[(k + 2) * 2 + 1] + a.w * Wls[(k + 3) * 2 + 1];
    }
    ((float2*)T)[v] = make_float2(acc0, acc1);
}

// Final aggregation, dim=2, one thread per node, writes d_out. (f32)
__global__ __launch_bounds__(256) void k_agg2(const float* __restrict__ T,
                                              const int* __restrict__ rowptr,
                                              const int* __restrict__ csr_src,
                                              const float* __restrict__ dis,
                                              const float* __restrict__ b3,
                                              float* __restrict__ out, int n) {
    int v = blockIdx.x * blockDim.x + threadIdx.x;
    if (v >= n) return;
    float dv = dis[v];
    float sw = dv * dv;
    float2 tv = ((const float2*)T)[v];
    float a0 = tv.x * sw, a1 = tv.y * sw;
    int end = rowptr[v + 1];
    for (int e = rowptr[v]; e < end; e++) {
        int s = csr_src[e];
        float w = dis[s] * dv;
        float2 hs = ((const float2*)T)[s];
        a0 += hs.x * w;
        a1 += hs.y * w;
    }
    ((float2*)out)[v] = make_float2(a0 + b3[0], a1 + b3[1]);
}

extern "C" void kernel_launch(void* const* d_in, const int* in_sizes, int n_in,
                              void* d_out, int out_size, void* d_ws, size_t ws_size,
                              hipStream_t stream) {
    const float* x  = (const float*)d_in[0];
    const int* edge = (const int*)d_in[1];
    const float* W1 = (const float*)d_in[2];
    const float* b1 = (const float*)d_in[3];
    const float* W2 = (const float*)d_in[4];
    const float* b2 = (const float*)d_in[5];
    const float* W3 = (const float*)d_in[6];
    const float* b3 = (const float*)d_in[7];

    const int n = in_sizes[0] / 128;   // 50000
    const int E = in_sizes[1] / 2;     // 800000
    const int* src = edge;
    const int* dst = edge + E;

    // Workspace carve (aligned 256B).
    char* p = (char*)d_ws;
    auto alloc = [&](size_t bytes) -> void* {
        void* r = (void*)p;
        p += ((bytes + 255) / 256) * 256;
        return r;
    };
    int*      cnt     = (int*)alloc((size_t)n * 4);
    int*      rowptr  = (int*)alloc((size_t)(n + 1) * 4);
    int*      cursor  = (int*)alloc((size_t)n * 4);
    float*    dis     = (float*)alloc((size_t)n * 4);
    int*      bsum    = (int*)alloc(256 * 4);
    int*      csr_src = (int*)alloc((size_t)E * 4);
    float*    t3      = (float*)alloc((size_t)n * 2 * 4);
    ushort_t* Hbf     = (ushort_t*)alloc((size_t)n * 128 * 2);  // bf16 features
    float*    Af      = (float*)alloc((size_t)n * 128 * 4);     // f32 agg output
    (void)ws_size;

    const int nscan = (n + 255) / 256;          // 196 blocks (<=256 required)
    const int eblk  = (E + 255) / 256;
    const int nblk  = (n + 255) / 256;

    // --- CSR build ---
    hipMemsetAsync(cnt, 0, (size_t)n * 4, stream);
    k_hist<<<eblk, 256, 0, stream>>>(dst, E, cnt);
    k_scanA<<<nscan, 256, 0, stream>>>(cnt, n, rowptr, bsum);
    k_scanB<<<1, 256, 0, stream>>>(bsum, nscan);
    k_scanC<<<nscan, 256, 0, stream>>>(rowptr, bsum, cnt, dis, cursor, n, E);
    k_fill<<<eblk, 256, 0, stream>>>(src, dst, E, cursor, csr_src);

    const int gblk = (n + 63) / 64;   // gemm128 blocks
    const int ablk = (n + 3) / 4;     // agg128 blocks (4 waves/block)

    // --- Layer 1 ---
    k_gemm128<<<gblk, 256, 0, stream>>>(x, W1, Hbf, n);
    k_agg128<<<ablk, 256, 0, stream>>>(Hbf, rowptr, csr_src, dis, b1, Af, n, 1);
    // --- Layer 2 ---
    k_gemm128<<<gblk, 256, 0, stream>>>(Af, W2, Hbf, n);
    k_agg128<<<ablk, 256, 0, stream>>>(Hbf, rowptr, csr_src, dis, b2, Af, n, 1);
    // --- Layer 3 (transform first: aggregation is linear) ---
    k_gemm_out<<<nblk, 256, 0, stream>>>(Af, W3, t3, n);
    k_agg2<<<nblk, 256, 0, stream>>>(t3, rowptr, csr_src, dis, b3, (float*)d_out, n);
}

// Round 10
// 301.007 us; speedup vs baseline: 1.3989x; 1.1587x over previous
//
#include <hip/hip_runtime.h>

// ---------------------------------------------------------------------------
// StandardGCN: 3-layer GCN, N=50000 nodes, E=800000 edges, D=H=128, OUT=2.
//   CSR build via deterministic 2-level bucket sort (NO global atomics):
//     bucket = dst >> 8 (NB = ceil(n/256) = 196 buckets).
//     k_bcount: per-block LDS hist of its edge chunk -> cntmat[blk][b] row.
//     k_bscan : column-exclusive-scan of cntmat (in place) + bucket scan ->
//               bktbase[NB+1]; rowptr[n] = E.
//     k_bfill : re-read chunk, LDS-claim slot in (blk,b) run, write packed
//               (src<<8 | d&255) into bucketed[] (runs => line-coalesced).
//     k_csort : one block/bucket: LDS counting sort by local d ->
//               coalesced csr_src write; rowptr[d], dis[d] computed here.
//   (replaces round-9's k_hist/k_fill whose 800k random 4B scatters cost
//    ~50us each at 64B/line write-allocate across 8 non-coherent L2s)
//   Layers: gemm128 (f32 compute -> bf16 H) -> pull-agg (bf16 gather, f32
//   accum); layer 3 transforms first (128->2) then aggregates.
//   Requires n <= 65536 (16-bit src packing) -- n = 50000.
// ---------------------------------------------------------------------------

typedef unsigned short ushort_t;
typedef unsigned int uint_t;

#define NBLK 128          // blocks for bcount/bfill
#define BCAP 6144         // per-bucket LDS capacity (mean 4096, +32 sigma)

static __device__ __forceinline__ ushort_t f2bf(float f) {
    uint_t u = __float_as_uint(f);
    u += 0x7FFFu + ((u >> 16) & 1u);   // round-to-nearest-even
    return (ushort_t)(u >> 16);
}
static __device__ __forceinline__ float bf_lo(uint_t u) {
    return __uint_as_float(u << 16);
}
static __device__ __forceinline__ float bf_hi(uint_t u) {
    return __uint_as_float(u & 0xFFFF0000u);
}

// --- pass 1: per-block bucket histogram (no global atomics) ---------------
__global__ __launch_bounds__(256) void k_bcount(const int* __restrict__ dst, int E,
                                                int* __restrict__ cntmat, int NB) {
    __shared__ int hist[256];
    int t = threadIdx.x;
    hist[t] = 0;
    __syncthreads();
    int chunk = (E + NBLK - 1) / NBLK;
    int e0 = blockIdx.x * chunk;
    int e1 = min(e0 + chunk, E);
    for (int e = e0 + t; e < e1; e += 256) {
        atomicAdd(&hist[dst[e] >> 8], 1);
    }
    __syncthreads();
    if (t < NB) cntmat[blockIdx.x * NB + t] = hist[t];
}

// --- pass 2: column scan of cntmat + bucket base scan ---------------------
__global__ __launch_bounds__(256) void k_bscan(int* __restrict__ cntmat,
                                               int* __restrict__ bktbase,
                                               int* __restrict__ rowptr,
                                               int NB, int n, int E) {
    __shared__ int s[256];
    int t = threadIdx.x;
    int acc = 0;
    if (t < NB) {
        for (int r = 0; r < NBLK; r++) {
            int idx = r * NB + t;
            int c = cntmat[idx];
            cntmat[idx] = acc;    // within-bucket cross-block exclusive offset
            acc += c;
        }
    }
    s[t] = acc;                   // column total (0 for t >= NB)
    __syncthreads();
    for (int off = 1; off < 256; off <<= 1) {
        int u = (t >= off) ? s[t - off] : 0;
        __syncthreads();
        s[t] += u;
        __syncthreads();
    }
    if (t <= NB) bktbase[t] = s[t] - ((t < NB) ? acc : 0);  // exclusive; [NB]=E
    if (t == 0) rowptr[n] = E;
}

// --- pass 3: binned scatter into bucketed[] (LDS claims, run-coalesced) ---
__global__ __launch_bounds__(256) void k_bfill(const int* __restrict__ src,
                                               const int* __restrict__ dst, int E,
                                               const int* __restrict__ cntmat,
                                               const int* __restrict__ bktbase,
                                               uint_t* __restrict__ bucketed, int NB) {
    __shared__ int runb[256];
    __shared__ int bb[257];
    __shared__ int cur[256];
    int t = threadIdx.x;
    if (t < NB) {
        runb[t] = cntmat[blockIdx.x * NB + t];
        cur[t] = 0;
    }
    if (t < NB + 1) bb[t] = bktbase[t];
    __syncthreads();
    int chunk = (E + NBLK - 1) / NBLK;
    int e0 = blockIdx.x * chunk;
    int e1 = min(e0 + chunk, E);
    for (int e = e0 + t; e < e1; e += 256) {
        int d = dst[e];
        int b = d >> 8;
        int slot = atomicAdd(&cur[b], 1);
        bucketed[bb[b] + runb[b] + slot] = ((uint_t)src[e] << 8) | (uint_t)(d & 255);
    }
}

// --- pass 4: per-bucket counting sort -> csr_src, rowptr, dis -------------
__global__ __launch_bounds__(256) void k_csort(const uint_t* __restrict__ bucketed,
                                               const int* __restrict__ bktbase,
                                               int* __restrict__ rowptr,
                                               float* __restrict__ dis,
                                               int* __restrict__ csr_src, int n) {
    __shared__ int ncnt[256];
    __shared__ int s[256];
    __shared__ int nofs[256];
    __shared__ int cur[256];
    __shared__ int sorted[BCAP];
    int t = threadIdx.x;
    int b = blockIdx.x;
    int base = bktbase[b];
    int cnt_b = bktbase[b + 1] - base;
    int d0 = b << 8;

    ncnt[t] = 0;
    __syncthreads();
    for (int i = t; i < cnt_b; i += 256) {
        atomicAdd(&ncnt[bucketed[base + i] & 255u], 1);
    }
    __syncthreads();
    int own = ncnt[t];
    s[t] = own;
    __syncthreads();
    for (int off = 1; off < 256; off <<= 1) {
        int u = (t >= off) ? s[t - off] : 0;
        __syncthreads();
        s[t] += u;
        __syncthreads();
    }
    int ex = s[t] - own;          // exclusive within-bucket offset
    nofs[t] = ex;
    cur[t] = ex;
    int d = d0 + t;
    if (d < n) {
        rowptr[d] = base + ex;
        dis[d] = rsqrtf((float)(own + 1));
    }
    __syncthreads();
    for (int i = t; i < cnt_b; i += 256) {
        uint_t ent = bucketed[base + i];
        int p = atomicAdd(&cur[ent & 255u], 1);
        if (p < BCAP) sorted[p] = (int)(ent >> 8);
    }
    __syncthreads();
    for (int i = t; i < cnt_b; i += 256) {
        csr_src[base + i] = sorted[i];
    }
}

// --- C[n x 128](bf16) = A[n x 128](f32) @ W[128 x 128](f32) ---------------
// 64 rows/block; LDS A-tile 32KB + W chunk 16KB = 48KB -> 3 blocks/CU.
__global__ __launch_bounds__(256) void k_gemm128(const float* __restrict__ A,
                                                 const float* __restrict__ W,
                                                 ushort_t* __restrict__ C, int n) {
    __shared__ float As[64 * 128];
    __shared__ float Wc[32 * 128];
    int t = threadIdx.x;
    int r0 = blockIdx.x * 64;

    for (int i = t; i < 64 * 128 / 4; i += 256) {
        int gr = r0 + (i >> 5);
        float4 val = (gr < n) ? ((const float4*)A)[(size_t)gr * 32 + (i & 31)]
                              : make_float4(0.f, 0.f, 0.f, 0.f);
        ((float4*)As)[i] = val;
    }

    int c4 = (t & 31) * 4;
    int r8 = (t >> 5) * 8;
    float acc[8][4] = {};

    for (int kc = 0; kc < 4; kc++) {
        __syncthreads();
        for (int i = t; i < 32 * 128 / 4; i += 256) {
            ((float4*)Wc)[i] = ((const float4*)W)[kc * 1024 + i];
        }
        __syncthreads();
#pragma unroll
        for (int kk = 0; kk < 32; kk++) {
            float4 w4 = *(const float4*)&Wc[kk * 128 + c4];
            int k = kc * 32 + kk;
#pragma unroll
            for (int i = 0; i < 8; i++) {
                float a = As[(r8 + i) * 128 + k];
                acc[i][0] += a * w4.x;
                acc[i][1] += a * w4.y;
                acc[i][2] += a * w4.z;
                acc[i][3] += a * w4.w;
            }
        }
    }
#pragma unroll
    for (int i = 0; i < 8; i++) {
        int r = r0 + r8 + i;
        if (r < n) {
            ushort4 o;
            o.x = f2bf(acc[i][0]);
            o.y = f2bf(acc[i][1]);
            o.z = f2bf(acc[i][2]);
            o.w = f2bf(acc[i][3]);
            *(ushort4*)&C[(size_t)r * 128 + c4] = o;
        }
    }
}

// --- pull aggregation, dim=128, bf16 H, f32 accumulate --------------------
__global__ __launch_bounds__(256) void k_agg128(const ushort_t* __restrict__ H,
                                                const int* __restrict__ rowptr,
                                                const int* __restrict__ csr_src,
                                                const float* __restrict__ dis,
                                                const float* __restrict__ bias,
                                                float* __restrict__ O, int n, int do_relu) {
    int wid = threadIdx.x >> 6;
    int lane = threadIdx.x & 63;
    int v = blockIdx.x * 4 + wid;
    if (v >= n) return;

    float dv = dis[v];
    float sw = dv * dv;
    uint_t h2 = ((const uint_t*)(H + (size_t)v * 128))[lane];
    float ax = bf_lo(h2) * sw, ay = bf_hi(h2) * sw;

    int e = rowptr[v], end = rowptr[v + 1];
    for (; e + 4 <= end; e += 4) {
        int s0 = csr_src[e], s1 = csr_src[e + 1], s2 = csr_src[e + 2], s3 = csr_src[e + 3];
        float w0 = dis[s0] * dv, w1 = dis[s1] * dv, w2 = dis[s2] * dv, w3 = dis[s3] * dv;
        uint_t a0 = ((const uint_t*)(H + (size_t)s0 * 128))[lane];
        uint_t a1 = ((const uint_t*)(H + (size_t)s1 * 128))[lane];
        uint_t a2 = ((const uint_t*)(H + (size_t)s2 * 128))[lane];
        uint_t a3 = ((const uint_t*)(H + (size_t)s3 * 128))[lane];
        ax += bf_lo(a0) * w0 + bf_lo(a1) * w1 + bf_lo(a2) * w2 + bf_lo(a3) * w3;
        ay += bf_hi(a0) * w0 + bf_hi(a1) * w1 + bf_hi(a2) * w2 + bf_hi(a3) * w3;
    }
    for (; e < end; e++) {
        int sI = csr_src[e];
        float w = dis[sI] * dv;
        uint_t a = ((const uint_t*)(H + (size_t)sI * 128))[lane];
        ax += bf_lo(a) * w;
        ay += bf_hi(a) * w;
    }

    float2 b2 = ((const float2*)bias)[lane];
    ax += b2.x;
    ay += b2.y;
    if (do_relu) {
        ax = fmaxf(ax, 0.f);
        ay = fmaxf(ay, 0.f);
    }
    ((float2*)(O + (size_t)v * 128))[lane] = make_float2(ax, ay);
}

// --- T[n x 2] = A[n x 128] @ W3[128 x 2] ----------------------------------
__global__ __launch_bounds__(256) void k_gemm_out(const float* __restrict__ A,
                                                  const float* __restrict__ W,
                                                  float* __restrict__ T, int n) {
    __shared__ float Wls[256];
    if (threadIdx.x < 256) Wls[threadIdx.x] = W[threadIdx.x];
    __syncthreads();
    int v = blockIdx.x * blockDim.x + threadIdx.x;
    if (v >= n) return;
    const float4* Av = (const float4*)(A + (size_t)v * 128);
    float acc0 = 0.f, acc1 = 0.f;
#pragma unroll
    for (int i = 0; i < 32; i++) {
        float4 a = Av[i];
        int k = i * 4;
        acc0 += a.x * Wls[(k + 0) * 2] + a.y * Wls[(k + 1) * 2] +
                a.z * Wls[(k + 2) * 2] + a.w * Wls[(k + 3) * 2];
        acc1 += a.x * Wls[(k + 0) * 2 + 1] + a.y * Wls[(k + 1) * 2 + 1] +
                a.z * Wls[(k + 2) * 2 + 1] + a.w * Wls[(k + 3) * 2 + 1];
    }
    ((float2*)T)[v] = make_float2(acc0, acc1);
}

// --- final aggregation, dim=2, writes d_out -------------------------------
__global__ __launch_bounds__(256) void k_agg2(const float* __restrict__ T,
                                              const int* __restrict__ rowptr,
                                              const int* __restrict__ csr_src,
                                              const float* __restrict__ dis,
                                              const float* __restrict__ b3,
                                              float* __restrict__ out, int n) {
    int v = blockIdx.x * blockDim.x + threadIdx.x;
    if (v >= n) return;
    float dv = dis[v];
    float sw = dv * dv;
    float2 tv = ((const float2*)T)[v];
    float a0 = tv.x * sw, a1 = tv.y * sw;
    int end = rowptr[v + 1];
    for (int e = rowptr[v]; e < end; e++) {
        int s = csr_src[e];
        float w = dis[s] * dv;
        float2 hs = ((const float2*)T)[s];
        a0 += hs.x * w;
        a1 += hs.y * w;
    }
    ((float2*)out)[v] = make_float2(a0 + b3[0], a1 + b3[1]);
}

extern "C" void kernel_launch(void* const* d_in, const int* in_sizes, int n_in,
                              void* d_out, int out_size, void* d_ws, size_t ws_size,
                              hipStream_t stream) {
    const float* x  = (const float*)d_in[0];
    const int* edge = (const int*)d_in[1];
    const float* W1 = (const float*)d_in[2];
    const float* b1 = (const float*)d_in[3];
    const float* W2 = (const float*)d_in[4];
    const float* b2 = (const float*)d_in[5];
    const float* W3 = (const float*)d_in[6];
    const float* b3 = (const float*)d_in[7];

    const int n = in_sizes[0] / 128;   // 50000
    const int E = in_sizes[1] / 2;     // 800000
    const int NB = (n + 255) >> 8;     // 196 buckets
    const int* src = edge;
    const int* dst = edge + E;

    // Workspace carve (aligned 256B). ~45.6 MB total.
    char* p = (char*)d_ws;
    auto alloc = [&](size_t bytes) -> void* {
        void* r = (void*)p;
        p += ((bytes + 255) / 256) * 256;
        return r;
    };
    int*      rowptr   = (int*)alloc((size_t)(n + 1) * 4);
    float*    dis      = (float*)alloc((size_t)n * 4);
    int*      cntmat   = (int*)alloc((size_t)NBLK * NB * 4);
    int*      bktbase  = (int*)alloc((size_t)(NB + 1) * 4);
    uint_t*   bucketed = (uint_t*)alloc((size_t)E * 4);
    int*      csr_src  = (int*)alloc((size_t)E * 4);
    float*    t3       = (float*)alloc((size_t)n * 2 * 4);
    ushort_t* Hbf      = (ushort_t*)alloc((size_t)n * 128 * 2);
    float*    Af       = (float*)alloc((size_t)n * 128 * 4);
    (void)ws_size;

    const int nblk = (n + 255) / 256;

    // --- CSR build (4 kernels, no global atomics) ---
    k_bcount<<<NBLK, 256, 0, stream>>>(dst, E, cntmat, NB);
    k_bscan<<<1, 256, 0, stream>>>(cntmat, bktbase, rowptr, NB, n, E);
    k_bfill<<<NBLK, 256, 0, stream>>>(src, dst, E, cntmat, bktbase, bucketed, NB);
    k_csort<<<NB, 256, 0, stream>>>(bucketed, bktbase, rowptr, dis, csr_src, n);

    const int gblk = (n + 63) / 64;
    const int ablk = (n + 3) / 4;

    // --- Layer 1 ---
    k_gemm128<<<gblk, 256, 0, stream>>>(x, W1, Hbf, n);
    k_agg128<<<ablk, 256, 0, stream>>>(Hbf, rowptr, csr_src, dis, b1, Af, n, 1);
    // --- Layer 2 ---
    k_gemm128<<<gblk, 256, 0, stream>>>(Af, W2, Hbf, n);
    k_agg128<<<ablk, 256, 0, stream>>>(Hbf, rowptr, csr_src, dis, b2, Af, n, 1);
    // --- Layer 3 (transform first: aggregation is linear) ---
    k_gemm_out<<<nblk, 256, 0, stream>>>(Af, W3, t3, n);
    k_agg2<<<nblk, 256, 0, stream>>>(t3, rowptr, csr_src, dis, b3, (float*)d_out, n);
}